// Round 8
// baseline (471.756 us; speedup 1.0000x reference)
//
#include <hip/hip_runtime.h>
#include <math.h>

constexpr int kNpts    = 72;
constexpr int kPriors  = 192;
constexpr int kLanes   = 4;
constexpr int kBatch   = 512;
constexpr int kStages  = 3;
constexpr int kD       = 6 + kNpts;           // 78
constexpr int kSamples = kStages * kBatch;    // 1536
constexpr int kGrid    = kSamples / 2;        // 768 blocks, 2 samples each

typedef unsigned long long u64;

__device__ __forceinline__ float smoothL1(float x) {
  float ax = fabsf(x);
  return ax < 1.0f ? 0.5f * x * x : ax - 0.5f;
}

// monotone map float -> uint32 (ascending order preserved, handles +/-inf)
__device__ __forceinline__ unsigned ordF(float f) {
  unsigned b = __float_as_uint(f);
  return (b & 0x80000000u) ? ~b : (b | 0x80000000u);
}

__device__ __forceinline__ void cswapA(u64& a, u64& b) {        // ascending
  if (b < a) { u64 t = a; a = b; b = t; }
}
__device__ __forceinline__ void cswapD(float& a, float& b) {    // descending
  if (b > a) { float t = a; a = b; b = t; }
}
__device__ __forceinline__ u64 umin64(u64 a, u64 b) { return a < b ? a : b; }
__device__ __forceinline__ u64 umax64(u64 a, u64 b) { return a < b ? b : a; }

__global__ __launch_bounds__(384, 7) void clr_loss_kernel(
    const float* __restrict__ pred,   // (3,512,192,78)
    const float* __restrict__ tgt,    // (512,4,78)
    float* __restrict__ partial) {    // (1536,) per-sample weighted value
  const int blk  = blockIdx.x;          // 0..767
  const int tid  = threadIdx.x;         // 0..383
  const int wav  = tid >> 6;            // 0..5
  const int lane = tid & 63;
  const int grp  = wav >= 3 ? 1 : 0;    // which sample half
  const int ltid = tid - grp * 192;     // 0..191 within group
  const int lwav = ltid >> 6;           // 0..2 within group
  const int smp  = 2 * blk + grp;       // 0..1535
  const int b    = smp & (kBatch - 1);

  __shared__ float s_tx[2][kNpts][kLanes];   // transposed target xs
  __shared__ float s_m [2][kNpts][kLanes];   // 0/1 validity mask
  __shared__ float s_hdr[2][kLanes][6];
  __shared__ float s_cost[2][kLanes][kPriors];
  __shared__ float s_iou[2][kLanes][kPriors];
  __shared__ u64   s_k3[2][kLanes][3];       // 3 smallest cost keys per column
  __shared__ int   s_dk[2][kLanes];          // dyn_k per column (1..3)
  __shared__ float s_sc[6][4];

  // ---- stage targets for both samples (transposed xs + mask) ----
  for (int t = tid; t < 2 * kLanes * kNpts; t += 384) {
    int g = t / (kLanes * kNpts);
    int r = t - g * (kLanes * kNpts);
    int j = r / kNpts, k = r - j * kNpts;
    float v = tgt[((size_t)((2 * blk + g) & (kBatch - 1)) * kLanes + j) * kD + 6 + k];
    s_tx[g][k][j] = v;
    s_m [g][k][j] = (v >= 0.0f && v < 800.0f) ? 1.0f : 0.0f;
  }
  if (tid < 2 * kLanes * 6) {
    int g = tid / (kLanes * 6);
    int r = tid - g * (kLanes * 6);
    int j = r / 6, c = r - j * 6;
    s_hdr[g][j][c] = tgt[((size_t)((2 * blk + g) & (kBatch - 1)) * kLanes + j) * kD + c];
  }
  if (tid >= 64 && tid < 64 + 2 * kLanes) {
    int t = tid - 64;
    int g = t / kLanes, j = t - g * kLanes;
    s_dk[g][j] = 1; s_k3[g][j][0] = 0; s_k3[g][j][1] = 0; s_k3[g][j][2] = 0;
  }

  // ---- burst-load my prior row (39 x float2, 8B aligned) ----
  const float2* rowv = (const float2*)(pred + ((size_t)smp * kPriors + ltid) * kD);
  float2 h0 = rowv[0], h1 = rowv[1], h2 = rowv[2];
  float px[kNpts];
#pragma unroll
  for (int q = 0; q < 36; ++q) {
    float2 v = rowv[3 + q];
    px[2 * q]     = v.x * 799.0f;
    px[2 * q + 1] = v.y * 799.0f;
  }
  const float p0 = h0.x, p1 = h0.y, p2 = h1.x, p3 = h1.y, p4 = h2.x, p5 = h2.y;

  __syncthreads();

  bool validL[kLanes];
  int num_t = 0;
#pragma unroll
  for (int j = 0; j < kLanes; ++j) {
    validL[j] = (s_hdr[grp][j][1] == 1.0f);
    num_t += validL[j] ? 1 : 0;
  }
  const bool has_t = num_t > 0;

  // ---- collapsed streaming pass: only dsum needed (2 VALU/elem) ----
  float ds[kLanes] = {0.0f, 0.0f, 0.0f, 0.0f};
  {
    const float4* tx4 = (const float4*)&s_tx[grp][0][0];
    const float4* m4  = (const float4*)&s_m[grp][0][0];
#pragma unroll
    for (int k = 0; k < kNpts; ++k) {
      float4 t = tx4[k];
      float4 m = m4[k];
      float p = px[k];
      ds[0] = fmaf(m.x, fabsf(t.x - p), ds[0]);
      ds[1] = fmaf(m.y, fabsf(t.y - p), ds[1]);
      ds[2] = fmaf(m.z, fabsf(t.z - p), ds[2]);
      ds[3] = fmaf(m.w, fabsf(t.w - p), ds[3]);
    }
  }

  // ---- per-lane scalars: iou/dist closed form; sd, th ----
  float iou[kLanes], dist[kLanes], sd[kLanes], th[kLanes];
  float md = -INFINITY, ms = -INFINITY, mt = -INFINITY;
  const float py = p2 * 319.0f, pxc = p3 * 799.0f;
#pragma unroll
  for (int j = 0; j < kLanes; ++j) {
    float tlen = validL[j] ? s_hdr[grp][j][5] : 0.0f;   // = valid point count
    float ovr = fmaf(tlen, 30.0f, -ds[j]);
    float uni = fmaf(tlen, 30.0f,  ds[j]) + 1e-9f;
    iou[j]  = ovr / uni;
    dist[j] = ds[j] / (tlen + 1e-9f);
    float dy = py - s_hdr[grp][j][2] * 319.0f;
    float dx = pxc - s_hdr[grp][j][3];
    sd[j] = sqrtf(dy * dy + dx * dx);
    th[j] = fabsf(p4 - s_hdr[grp][j][4]) * 180.0f;
    if (validL[j]) {
      md = fmaxf(md, dist[j]);
      ms = fmaxf(ms, sd[j]);
      mt = fmaxf(mt, th[j]);
    }
  }

  // ---- per-sample max reduce for norm_score denominators ----
#pragma unroll
  for (int off = 32; off; off >>= 1) {
    md = fmaxf(md, __shfl_down(md, off, 64));
    ms = fmaxf(ms, __shfl_down(ms, off, 64));
    mt = fmaxf(mt, __shfl_down(mt, off, 64));
  }
  if (lane == 0) { s_sc[wav][0] = md; s_sc[wav][1] = ms; s_sc[wav][2] = mt; }
  __syncthreads();
  {
    const int w0 = 3 * grp;
    md = fmaxf(fmaxf(s_sc[w0][0], s_sc[w0 + 1][0]), s_sc[w0 + 2][0]);
    ms = fmaxf(fmaxf(s_sc[w0][1], s_sc[w0 + 1][1]), s_sc[w0 + 2][1]);
    mt = fmaxf(fmaxf(s_sc[w0][2], s_sc[w0 + 1][2]), s_sc[w0 + 2][2]);
  }
  if (!has_t) { md = 1.0f; ms = 1.0f; mt = 1.0f; }

  // ---- cls_cost ----
  const float sp1  = 1.0f / (1.0f + expf(-p1));
  const float neg1 = -logf(1.0f - sp1 + 1e-12f) * 0.75f * sp1 * sp1;
  const float om1  = 1.0f - sp1;
  const float pos1 = -logf(sp1 + 1e-12f) * 0.25f * om1 * om1;
  const float cls_cost = pos1 - neg1;

  // ---- cost matrix + iou_sg into LDS ----
  float costr[kLanes];
#pragma unroll
  for (int j = 0; j < kLanes; ++j) {
    s_iou[grp][j][ltid] = validL[j] ? fmaxf(iou[j], 0.0f) : 0.0f;
    float c;
    if (validL[j]) {
      float a = (1.0f - dist[j] / md) + 0.01f;
      float s = (1.0f - sd[j] / ms) + 0.01f;
      float t = (1.0f - th[j] / mt) + 0.01f;
      float g = a * s * t;
      c = cls_cost - g * g * 3.0f;
    } else {
      c = INFINITY;
    }
    costr[j] = c;
    s_cost[grp][j][ltid] = c;
  }
  __syncthreads();

  // ---- 8 selection tasks (4 cost min-3, 4 iou top-4) over 3 waves/group ----
  for (int t = lwav; t < 8; t += 3) {
    const int j = t & 3;
    if (!validL[j]) continue;            // group-uniform
    if (t < 4) {
      // 3-reg min-3 butterfly on distinct ordered u64 keys
      float c0 = s_cost[grp][j][lane], c1 = s_cost[grp][j][lane + 64],
            c2 = s_cost[grp][j][lane + 128];
      u64 k0 = ((u64)ordF(c0) << 32) | (unsigned)lane;
      u64 k1 = ((u64)ordF(c1) << 32) | (unsigned)(lane + 64);
      u64 k2 = ((u64)ordF(c2) << 32) | (unsigned)(lane + 128);
      cswapA(k0, k1); cswapA(k0, k2); cswapA(k1, k2);
#pragma unroll
      for (int off = 1; off < 64; off <<= 1) {
        u64 b0 = __shfl_xor(k0, off), b1 = __shfl_xor(k1, off), b2 = __shfl_xor(k2, off);
        u64 x0 = umin64(k0, b0), y0 = umax64(k0, b0);
        u64 x1 = umin64(k1, b1);
        u64 mc = umin64(k2, b2);
        k0 = x0;
        k2 = umin64(umax64(y0, x1), mc);
        k1 = umin64(y0, x1);
      }
      if (lane == 0) { s_k3[grp][j][0] = k0; s_k3[grp][j][1] = k1; s_k3[grp][j][2] = k2; }
    } else {
      // 4-reg top-4 (descending) butterfly, f32
      float t0 = s_iou[grp][j][lane], t1 = s_iou[grp][j][lane + 64],
            t2 = s_iou[grp][j][lane + 128];
      float t3 = -1.0f;
      cswapD(t0, t1); cswapD(t0, t2); cswapD(t1, t2);
#pragma unroll
      for (int off = 1; off < 64; off <<= 1) {
        float b0 = __shfl_xor(t0, off), b1 = __shfl_xor(t1, off);
        float b2 = __shfl_xor(t2, off), b3 = __shfl_xor(t3, off);
        float m0 = fmaxf(t0, b3), m1 = fmaxf(t1, b2);
        float m2 = fmaxf(t2, b1), m3 = fmaxf(t3, b0);
        cswapD(m0, m2); cswapD(m1, m3); cswapD(m0, m1); cswapD(m2, m3);
        t0 = m0; t1 = m1; t2 = m2; t3 = m3;
      }
      if (lane == 0) {
        float s = ((t0 + t1) + t2) + t3;   // descending order, matches top_k sum
        int dk = (int)s;                   // iou < 1 strictly => s < 4 => dk <= 3
        if (dk < 1) dk = 1;
        if (dk > 3) dk = 3;
        s_dk[grp][j] = dk;
      }
    }
  }
  __syncthreads();

  // ---- membership: stable-rank < dyn_k  <=>  key <= dyn_k-th smallest key ----
  int Mi[kLanes];
  int msum = 0;
#pragma unroll
  for (int j = 0; j < kLanes; ++j) {
    u64 myk = ((u64)ordF(costr[j]) << 32) | (unsigned)ltid;
    Mi[j] = (validL[j] && myk <= s_k3[grp][j][s_dk[grp][j] - 1]) ? 1 : 0;
    msum += Mi[j];
  }

  // argmin over lanes (first-min semantics)
  float amin = costr[0];
  int aidx = 0;
#pragma unroll
  for (int j = 1; j < kLanes; ++j)
    if (costr[j] < amin) { amin = costr[j]; aidx = j; }

  float Mf[kLanes];
#pragma unroll
  for (int j = 0; j < kLanes; ++j) Mf[j] = (float)Mi[j];
  if (msum > 1) {
    Mf[0] = 0.0f;
    Mf[aidx] = 1.0f;
  }

  const float mfsum = Mf[0] + Mf[1] + Mf[2] + Mf[3];
  const int cls_t = (mfsum > 0.0f) ? 1 : 0;

  // ---- focal classification term ----
  const float mx = fmaxf(p0, p1);
  const float e0 = expf(p0 - mx), e1 = expf(p1 - mx);
  const float inv = 1.0f / (e0 + e1);
  const float q = (cls_t ? e1 : e0) * inv + 1e-8f;
  const float omq = 1.0f - q;
  const float focal = -0.25f * omq * omq * logf(q);

  // ---- reg (smooth L1) + iou terms for matched pairs ----
  const float pred_start = fminf(fmaxf(rintf(p2 * 71.0f), 0.0f), 71.0f);
  const float py0 = p2 * 71.0f, py1 = p3 * 799.0f, py2t = p4 * 180.0f, py3 = p5 * 71.0f;
  float regc = 0.0f, iouc = 0.0f;
#pragma unroll
  for (int j = 0; j < kLanes; ++j) {
    if (Mf[j] > 0.0f) {
      float t30 = s_hdr[grp][j][2] * 71.0f;
      float t31 = s_hdr[grp][j][3];
      float t32 = s_hdr[grp][j][4] * 180.0f;
      float tstart = rintf(s_hdr[grp][j][2] * 71.0f);
      float tlp = s_hdr[grp][j][5] - (pred_start - tstart);
      regc += smoothL1(py0 - t30) + smoothL1(py1 - t31) + smoothL1(py2t - t32)
            + smoothL1(py3 - tlp);
      iouc += 1.0f - iou[j];
    }
  }

  // ---- per-sample sum reduce (4 values) ----
  float v0 = mfsum, v1 = focal, v2 = regc, v3 = iouc;
#pragma unroll
  for (int off = 32; off; off >>= 1) {
    v0 += __shfl_down(v0, off, 64);
    v1 += __shfl_down(v1, off, 64);
    v2 += __shfl_down(v2, off, 64);
    v3 += __shfl_down(v3, off, 64);
  }
  __syncthreads();   // s_sc reuse hazard
  if (lane == 0) {
    s_sc[wav][0] = v0; s_sc[wav][1] = v1; s_sc[wav][2] = v2; s_sc[wav][3] = v3;
  }
  __syncthreads();

  if (ltid == 0) {
    const int w0 = 3 * grp;
    float nm      = s_sc[w0][0] + s_sc[w0 + 1][0] + s_sc[w0 + 2][0];
    float cls_sum = s_sc[w0][1] + s_sc[w0 + 1][1] + s_sc[w0 + 2][1];
    float reg_sum = s_sc[w0][2] + s_sc[w0 + 1][2] + s_sc[w0 + 2][2];
    float iou_sum = s_sc[w0][3] + s_sc[w0 + 1][3] + s_sc[w0 + 2][3];

    float cls_term = cls_sum / (has_t ? (float)num_t : 1.0f);
    float reg_term = has_t ? reg_sum / fmaxf(nm * 4.0f, 1.0f) : 0.0f;
    float iou_term = has_t ? iou_sum / fmaxf(nm, 1.0f) : 0.0f;

    partial[smp] = 2.0f * cls_term + 0.2f * reg_term + 2.0f * iou_term;
  }
}

__global__ __launch_bounds__(256) void clr_reduce(
    const float* __restrict__ partial,   // (1536,)
    const float* __restrict__ seg,
    float* __restrict__ out) {
  const int tid  = threadIdx.x;
  const int wav  = tid >> 6;
  const int lane = tid & 63;
  __shared__ float sc[4];

  float s = 0.0f;
#pragma unroll
  for (int i = 0; i < kSamples / 256; ++i) s += partial[tid + 256 * i];
#pragma unroll
  for (int off = 32; off; off >>= 1) s += __shfl_down(s, off, 64);
  if (lane == 0) sc[wav] = s;
  __syncthreads();
  if (tid == 0) {
    float tot = ((sc[0] + sc[1]) + sc[2]) + sc[3];
    out[0] = tot * (1.0f / (float)kSamples) + seg[0];
  }
}

extern "C" void kernel_launch(void* const* d_in, const int* in_sizes, int n_in,
                              void* d_out, int out_size, void* d_ws, size_t ws_size,
                              hipStream_t stream) {
  const float* pred = (const float*)d_in[0];   // (3,512,192,78) f32
  const float* tgt  = (const float*)d_in[1];   // (512,4,78) f32
  const float* seg  = (const float*)d_in[2];   // scalar f32
  float* out     = (float*)d_out;              // scalar f32
  float* partial = (float*)d_ws;               // 1536 floats of scratch

  clr_loss_kernel<<<kGrid, 384, 0, stream>>>(pred, tgt, partial);
  clr_reduce<<<1, 256, 0, stream>>>(partial, seg, out);
}

// Round 9
// 148.041 us; speedup vs baseline: 3.1867x; 3.1867x over previous
//
#include <hip/hip_runtime.h>
#include <math.h>

constexpr int kNpts    = 72;
constexpr int kPriors  = 192;
constexpr int kLanes   = 4;
constexpr int kBatch   = 512;
constexpr int kStages  = 3;
constexpr int kD       = 6 + kNpts;           // 78
constexpr int kSamples = kStages * kBatch;    // 1536

typedef unsigned long long u64;

__device__ __forceinline__ float smoothL1(float x) {
  float ax = fabsf(x);
  return ax < 1.0f ? 0.5f * x * x : ax - 0.5f;
}

// monotone map float -> uint32 (ascending order preserved, handles +/-inf)
__device__ __forceinline__ unsigned ordF(float f) {
  unsigned b = __float_as_uint(f);
  return (b & 0x80000000u) ? ~b : (b | 0x80000000u);
}

__device__ __forceinline__ void cswapA(u64& a, u64& b) {        // ascending
  if (b < a) { u64 t = a; a = b; b = t; }
}
__device__ __forceinline__ void cswapD(float& a, float& b) {    // descending
  if (b > a) { float t = a; a = b; b = t; }
}
__device__ __forceinline__ u64 umin64(u64 a, u64 b) { return a < b ? a : b; }
__device__ __forceinline__ u64 umax64(u64 a, u64 b) { return a < b ? b : a; }

__global__ __launch_bounds__(192) void clr_loss_kernel(
    const float* __restrict__ pred,   // (3,512,192,78)
    const float* __restrict__ tgt,    // (512,4,78)
    float* __restrict__ partial) {    // (1536,) per-sample weighted value
  const int blk  = blockIdx.x;          // stage*512 + b
  const int b    = blk & (kBatch - 1);
  const int tid  = threadIdx.x;         // one prior per thread
  const int wav  = tid >> 6;
  const int lane = tid & 63;

  __shared__ float s_cost[kLanes][kPriors];
  __shared__ float s_iou[kLanes][kPriors];
  __shared__ u64   s_k3[kLanes][3];       // 3 smallest cost keys per column
  __shared__ int   s_dk[kLanes];          // dyn_k per column (1..3)
  __shared__ float s_sc[3][4];

  if (tid >= 64 && tid < 64 + kLanes) {
    int j = tid - 64;
    s_dk[j] = 1; s_k3[j][0] = 0; s_k3[j][1] = 0; s_k3[j][2] = 0;
  }

  // ---- block-uniform target pointer: all tgt reads become s_load (SGPR) ----
  const float* tg = tgt + (size_t)b * kLanes * kD;

  bool validL[kLanes];
  float hdr2[kLanes], hdr3[kLanes], hdr4[kLanes], hdr5[kLanes];
  int num_t = 0;
#pragma unroll
  for (int j = 0; j < kLanes; ++j) {
    validL[j] = (tg[j * kD + 1] == 1.0f);   // uniform -> SGPR
    hdr2[j] = tg[j * kD + 2];
    hdr3[j] = tg[j * kD + 3];
    hdr4[j] = tg[j * kD + 4];
    hdr5[j] = tg[j * kD + 5];
    num_t += validL[j] ? 1 : 0;
  }
  const bool has_t = num_t > 0;

  // ---- burst-load my prior row (39 x float2, 8B aligned) ----
  const float2* rowv = (const float2*)(pred + ((size_t)blk * kPriors + tid) * kD);
  float2 h0 = rowv[0], h1 = rowv[1], h2 = rowv[2];
  float px[kNpts];
#pragma unroll
  for (int q = 0; q < 36; ++q) {
    float2 v = rowv[3 + q];
    px[2 * q]     = v.x * 799.0f;
    px[2 * q + 1] = v.y * 799.0f;
  }
  const float p0 = h0.x, p1 = h0.y, p2 = h1.x, p3 = h1.y, p4 = h2.x, p5 = h2.y;

  // ---- streaming pass: tx from SGPRs, mask folded via med3 (bitwise == R6) ----
  // invalid tx = -100000 => |d| ~ 1e5 => med3(|d|,0,2000-|d|)=0 ; valid => |d|<800 => med3=|d|
  float ds[kLanes];
#pragma unroll
  for (int j = 0; j < kLanes; ++j) {
    const float* txj = tg + j * kD + 6;    // uniform -> s_load_dwordx16 batches
    float acc = 0.0f;
#pragma unroll
    for (int k = 0; k < kNpts; ++k) {
      float d  = txj[k] - px[k];
      float ad = fabsf(d);
      acc += __builtin_amdgcn_fmed3f(ad, 0.0f, 2000.0f - ad);
    }
    ds[j] = acc;
  }

  // ---- per-lane scalars: iou/dist closed form; sd, th ----
  float iou[kLanes], dist[kLanes], sd[kLanes], th[kLanes];
  float md = -INFINITY, ms = -INFINITY, mt = -INFINITY;
  const float py = p2 * 319.0f, pxc = p3 * 799.0f;
#pragma unroll
  for (int j = 0; j < kLanes; ++j) {
    float tlen = validL[j] ? hdr5[j] : 0.0f;   // = valid point count
    float ovr = fmaf(tlen, 30.0f, -ds[j]);
    float uni = fmaf(tlen, 30.0f,  ds[j]) + 1e-9f;
    iou[j]  = ovr / uni;
    dist[j] = ds[j] / (tlen + 1e-9f);
    float dy = py - hdr2[j] * 319.0f;
    float dx = pxc - hdr3[j];
    sd[j] = sqrtf(dy * dy + dx * dx);
    th[j] = fabsf(p4 - hdr4[j]) * 180.0f;
    if (validL[j]) {
      md = fmaxf(md, dist[j]);
      ms = fmaxf(ms, sd[j]);
      mt = fmaxf(mt, th[j]);
    }
  }

  // ---- block max reduce for norm_score denominators ----
#pragma unroll
  for (int off = 32; off; off >>= 1) {
    md = fmaxf(md, __shfl_down(md, off, 64));
    ms = fmaxf(ms, __shfl_down(ms, off, 64));
    mt = fmaxf(mt, __shfl_down(mt, off, 64));
  }
  if (lane == 0) { s_sc[wav][0] = md; s_sc[wav][1] = ms; s_sc[wav][2] = mt; }
  __syncthreads();
  md = fmaxf(fmaxf(s_sc[0][0], s_sc[1][0]), s_sc[2][0]);
  ms = fmaxf(fmaxf(s_sc[0][1], s_sc[1][1]), s_sc[2][1]);
  mt = fmaxf(fmaxf(s_sc[0][2], s_sc[1][2]), s_sc[2][2]);
  if (!has_t) { md = 1.0f; ms = 1.0f; mt = 1.0f; }

  // ---- cls_cost ----
  const float sp1  = 1.0f / (1.0f + expf(-p1));
  const float neg1 = -logf(1.0f - sp1 + 1e-12f) * 0.75f * sp1 * sp1;
  const float om1  = 1.0f - sp1;
  const float pos1 = -logf(sp1 + 1e-12f) * 0.25f * om1 * om1;
  const float cls_cost = pos1 - neg1;

  // ---- cost matrix + iou_sg into LDS ----
  float costr[kLanes];
#pragma unroll
  for (int j = 0; j < kLanes; ++j) {
    s_iou[j][tid] = validL[j] ? fmaxf(iou[j], 0.0f) : 0.0f;
    float c;
    if (validL[j]) {
      float a = (1.0f - dist[j] / md) + 0.01f;
      float s = (1.0f - sd[j] / ms) + 0.01f;
      float t = (1.0f - th[j] / mt) + 0.01f;
      float g = a * s * t;
      c = cls_cost - g * g * 3.0f;
    } else {
      c = INFINITY;
    }
    costr[j] = c;
    s_cost[j][tid] = c;
  }
  __syncthreads();

  // ---- 8 selection tasks (4 cost min-3, 4 iou top-4) over 3 waves ----
  for (int t = wav; t < 8; t += 3) {
    const int j = t & 3;
    if (!validL[j]) continue;            // block-uniform
    if (t < 4) {
      // 3-reg min-3 butterfly on distinct ordered u64 keys
      float c0 = s_cost[j][lane], c1 = s_cost[j][lane + 64], c2 = s_cost[j][lane + 128];
      u64 k0 = ((u64)ordF(c0) << 32) | (unsigned)lane;
      u64 k1 = ((u64)ordF(c1) << 32) | (unsigned)(lane + 64);
      u64 k2 = ((u64)ordF(c2) << 32) | (unsigned)(lane + 128);
      cswapA(k0, k1); cswapA(k0, k2); cswapA(k1, k2);
#pragma unroll
      for (int off = 1; off < 64; off <<= 1) {
        u64 b0 = __shfl_xor(k0, off), b1 = __shfl_xor(k1, off), b2 = __shfl_xor(k2, off);
        u64 x0 = umin64(k0, b0), y0 = umax64(k0, b0);
        u64 x1 = umin64(k1, b1);
        u64 mc = umin64(k2, b2);
        k0 = x0;
        k2 = umin64(umax64(y0, x1), mc);
        k1 = umin64(y0, x1);
      }
      if (lane == 0) { s_k3[j][0] = k0; s_k3[j][1] = k1; s_k3[j][2] = k2; }
    } else {
      // 4-reg top-4 (descending) butterfly, f32
      float t0 = s_iou[j][lane], t1 = s_iou[j][lane + 64], t2 = s_iou[j][lane + 128];
      float t3 = -1.0f;
      cswapD(t0, t1); cswapD(t0, t2); cswapD(t1, t2);
#pragma unroll
      for (int off = 1; off < 64; off <<= 1) {
        float b0 = __shfl_xor(t0, off), b1 = __shfl_xor(t1, off);
        float b2 = __shfl_xor(t2, off), b3 = __shfl_xor(t3, off);
        float m0 = fmaxf(t0, b3), m1 = fmaxf(t1, b2);
        float m2 = fmaxf(t2, b1), m3 = fmaxf(t3, b0);
        cswapD(m0, m2); cswapD(m1, m3); cswapD(m0, m1); cswapD(m2, m3);
        t0 = m0; t1 = m1; t2 = m2; t3 = m3;
      }
      if (lane == 0) {
        float s = ((t0 + t1) + t2) + t3;   // descending order, matches top_k sum
        int dk = (int)s;                   // iou < 1 strictly => s < 4 => dk <= 3
        if (dk < 1) dk = 1;
        if (dk > 3) dk = 3;
        s_dk[j] = dk;
      }
    }
  }
  __syncthreads();

  // ---- membership: stable-rank < dyn_k  <=>  key <= dyn_k-th smallest key ----
  int Mi[kLanes];
  int msum = 0;
#pragma unroll
  for (int j = 0; j < kLanes; ++j) {
    u64 myk = ((u64)ordF(costr[j]) << 32) | (unsigned)tid;
    Mi[j] = (validL[j] && myk <= s_k3[j][s_dk[j] - 1]) ? 1 : 0;
    msum += Mi[j];
  }

  // argmin over lanes (first-min semantics)
  float amin = costr[0];
  int aidx = 0;
#pragma unroll
  for (int j = 1; j < kLanes; ++j)
    if (costr[j] < amin) { amin = costr[j]; aidx = j; }

  float Mf[kLanes];
#pragma unroll
  for (int j = 0; j < kLanes; ++j) Mf[j] = (float)Mi[j];
  if (msum > 1) {
    Mf[0] = 0.0f;
    Mf[aidx] = 1.0f;
  }

  const float mfsum = Mf[0] + Mf[1] + Mf[2] + Mf[3];
  const int cls_t = (mfsum > 0.0f) ? 1 : 0;

  // ---- focal classification term ----
  const float mx = fmaxf(p0, p1);
  const float e0 = expf(p0 - mx), e1 = expf(p1 - mx);
  const float inv = 1.0f / (e0 + e1);
  const float q = (cls_t ? e1 : e0) * inv + 1e-8f;
  const float omq = 1.0f - q;
  const float focal = -0.25f * omq * omq * logf(q);

  // ---- reg (smooth L1) + iou terms for matched pairs ----
  const float pred_start = fminf(fmaxf(rintf(p2 * 71.0f), 0.0f), 71.0f);
  const float py0 = p2 * 71.0f, py1 = p3 * 799.0f, py2t = p4 * 180.0f, py3 = p5 * 71.0f;
  float regc = 0.0f, iouc = 0.0f;
#pragma unroll
  for (int j = 0; j < kLanes; ++j) {
    if (Mf[j] > 0.0f) {
      float t30 = hdr2[j] * 71.0f;
      float t31 = hdr3[j];
      float t32 = hdr4[j] * 180.0f;
      float tstart = rintf(hdr2[j] * 71.0f);
      float tlp = hdr5[j] - (pred_start - tstart);
      regc += smoothL1(py0 - t30) + smoothL1(py1 - t31) + smoothL1(py2t - t32)
            + smoothL1(py3 - tlp);
      iouc += 1.0f - iou[j];
    }
  }

  // ---- block sum reduce (4 values) ----
  float v0 = mfsum, v1 = focal, v2 = regc, v3 = iouc;
#pragma unroll
  for (int off = 32; off; off >>= 1) {
    v0 += __shfl_down(v0, off, 64);
    v1 += __shfl_down(v1, off, 64);
    v2 += __shfl_down(v2, off, 64);
    v3 += __shfl_down(v3, off, 64);
  }
  __syncthreads();   // s_sc reuse hazard
  if (lane == 0) {
    s_sc[wav][0] = v0; s_sc[wav][1] = v1; s_sc[wav][2] = v2; s_sc[wav][3] = v3;
  }
  __syncthreads();

  if (tid == 0) {
    float nm      = s_sc[0][0] + s_sc[1][0] + s_sc[2][0];
    float cls_sum = s_sc[0][1] + s_sc[1][1] + s_sc[2][1];
    float reg_sum = s_sc[0][2] + s_sc[1][2] + s_sc[2][2];
    float iou_sum = s_sc[0][3] + s_sc[1][3] + s_sc[2][3];

    float cls_term = cls_sum / (has_t ? (float)num_t : 1.0f);
    float reg_term = has_t ? reg_sum / fmaxf(nm * 4.0f, 1.0f) : 0.0f;
    float iou_term = has_t ? iou_sum / fmaxf(nm, 1.0f) : 0.0f;

    partial[blk] = 2.0f * cls_term + 0.2f * reg_term + 2.0f * iou_term;
  }
}

__global__ __launch_bounds__(256) void clr_reduce(
    const float* __restrict__ partial,   // (1536,)
    const float* __restrict__ seg,
    float* __restrict__ out) {
  const int tid  = threadIdx.x;
  const int wav  = tid >> 6;
  const int lane = tid & 63;
  __shared__ float sc[4];

  float s = 0.0f;
#pragma unroll
  for (int i = 0; i < kSamples / 256; ++i) s += partial[tid + 256 * i];
#pragma unroll
  for (int off = 32; off; off >>= 1) s += __shfl_down(s, off, 64);
  if (lane == 0) sc[wav] = s;
  __syncthreads();
  if (tid == 0) {
    float tot = ((sc[0] + sc[1]) + sc[2]) + sc[3];
    out[0] = tot * (1.0f / (float)kSamples) + seg[0];
  }
}

extern "C" void kernel_launch(void* const* d_in, const int* in_sizes, int n_in,
                              void* d_out, int out_size, void* d_ws, size_t ws_size,
                              hipStream_t stream) {
  const float* pred = (const float*)d_in[0];   // (3,512,192,78) f32
  const float* tgt  = (const float*)d_in[1];   // (512,4,78) f32
  const float* seg  = (const float*)d_in[2];   // scalar f32
  float* out     = (float*)d_out;              // scalar f32
  float* partial = (float*)d_ws;               // 1536 floats of scratch

  clr_loss_kernel<<<kSamples, 192, 0, stream>>>(pred, tgt, partial);
  clr_reduce<<<1, 256, 0, stream>>>(partial, seg, out);
}